// Round 3
// baseline (259.767 us; speedup 1.0000x reference)
//
#include <hip/hip_runtime.h>
#include <math.h>

// RotaryEmbedding: x (4,16,8192,64) fp32. Rotate first ROTATE=4 pairs
// (elements 0..7) of last dim; copy elements 8..63 through.
//
// R2 post-mortem: transcendentals are free (latency-hidden); dur_us is
// dominated by ~160us of harness fill/restore dispatches (all top-5 rocprof
// rows are 512MiB fillBuffer kernels at ~80us). Our kernel is <79us but its
// exact duration is hidden below the top-k cutoff.
//
// R3 = DIAGNOSTIC: launch the (idempotent, in->out) hot kernel TWICE.
// dur_R3 - 223.6 (R1 single-launch baseline) = exact hot-kernel duration.
// Floor: 268 MB @ 6.3 TB/s = 43 us.

#define DIM 64
#define F4_PER_ROW (DIM / 4)   // 16

__global__ __launch_bounds__(256) void rope_kernel(
    const float4* __restrict__ x,
    const float* __restrict__ dparam,
    const float* __restrict__ thetas,
    float4* __restrict__ out,
    int n4)
{
    int idx = blockIdx.x * blockDim.x + threadIdx.x;
    if (idx >= n4) return;

    float4 v = x[idx];
    int pos = idx & (F4_PER_ROW - 1);   // position within the 64-float row

    if (pos < 2) {
        // pairs handled by this float4: p0 = pos*2, p0+1
        float direction = tanhf(dparam[0] * 0.5f);  // sigmoid(d)*2-1
        int p0 = pos * 2;
        float t0 = direction * thetas[p0];
        float t1 = direction * thetas[p0 + 1];
        float c0 = cosf(t0), s0 = sinf(t0);
        float c1 = cosf(t1), s1 = sinf(t1);
        float xi0 = v.x, xj0 = v.y;
        float xi1 = v.z, xj1 = v.w;
        v.x = fmaf(xi0, c0,  xj0 * s0);
        v.y = fmaf(xj0, c0, -xi0 * s0);
        v.z = fmaf(xi1, c1,  xj1 * s1);
        v.w = fmaf(xj1, c1, -xi1 * s1);
    }

    out[idx] = v;
}

extern "C" void kernel_launch(void* const* d_in, const int* in_sizes, int n_in,
                              void* d_out, int out_size, void* d_ws, size_t ws_size,
                              hipStream_t stream)
{
    const float* x      = (const float*)d_in[0];
    const float* dparam = (const float*)d_in[1];
    const float* thetas = (const float*)d_in[2];
    float* out          = (float*)d_out;

    int n  = in_sizes[0];        // 33,554,432
    int n4 = n / 4;              // 8,388,608 float4s

    const int block = 256;
    int grid = (n4 + block - 1) / block;

    // Launch TWICE (diagnostic): kernel reads only d_in and writes d_out,
    // so the second application produces the identical result.
    rope_kernel<<<grid, block, 0, stream>>>(
        (const float4*)x, dparam, thetas, (float4*)out, n4);
    rope_kernel<<<grid, block, 0, stream>>>(
        (const float4*)x, dparam, thetas, (float4*)out, n4);
}

// Round 4
// 220.338 us; speedup vs baseline: 1.1789x; 1.1789x over previous
//
#include <hip/hip_runtime.h>
#include <math.h>

// RotaryEmbedding: x (4,16,8192,64) fp32. Rotate first ROTATE=4 pairs
// (elements 0..7) of last dim; copy elements 8..63 through.
//
// Final form (R1 structure, R3-validated):
//  - One thread per float4 (16B/lane coalesced). Only pos 0,1 of each
//    16-float4 row rotate; transcendentals in the masked branch are
//    latency-hidden behind memory (R2 A/B: precompute split was neutral).
//  - R3 double-launch probe measured the hot kernel at ~36us warm
//    (LLC-resident input) / ~45us cold = the 268MB traffic floor.
//    The remaining ~178us of dur_us is harness restore/poison fills
//    (512MiB fillBuffer dispatches at 6.6 TB/s) - untouchable.

#define DIM 64
#define F4_PER_ROW (DIM / 4)   // 16

__global__ __launch_bounds__(256) void rope_kernel(
    const float4* __restrict__ x,
    const float* __restrict__ dparam,
    const float* __restrict__ thetas,
    float4* __restrict__ out,
    int n4)
{
    int idx = blockIdx.x * blockDim.x + threadIdx.x;
    if (idx >= n4) return;

    float4 v = x[idx];
    int pos = idx & (F4_PER_ROW - 1);   // position within the 64-float row

    if (pos < 2) {
        // pairs handled by this float4: p0 = pos*2, p0+1
        float direction = tanhf(dparam[0] * 0.5f);  // sigmoid(d)*2-1
        int p0 = pos * 2;
        float t0 = direction * thetas[p0];
        float t1 = direction * thetas[p0 + 1];
        float c0 = cosf(t0), s0 = sinf(t0);
        float c1 = cosf(t1), s1 = sinf(t1);
        float xi0 = v.x, xj0 = v.y;
        float xi1 = v.z, xj1 = v.w;
        v.x = fmaf(xi0, c0,  xj0 * s0);
        v.y = fmaf(xj0, c0, -xi0 * s0);
        v.z = fmaf(xi1, c1,  xj1 * s1);
        v.w = fmaf(xj1, c1, -xi1 * s1);
    }

    out[idx] = v;
}

extern "C" void kernel_launch(void* const* d_in, const int* in_sizes, int n_in,
                              void* d_out, int out_size, void* d_ws, size_t ws_size,
                              hipStream_t stream)
{
    const float* x      = (const float*)d_in[0];
    const float* dparam = (const float*)d_in[1];
    const float* thetas = (const float*)d_in[2];
    float* out          = (float*)d_out;

    int n  = in_sizes[0];        // 33,554,432
    int n4 = n / 4;              // 8,388,608 float4s

    const int block = 256;
    int grid = (n4 + block - 1) / block;

    rope_kernel<<<grid, block, 0, stream>>>(
        (const float4*)x, dparam, thetas, (float4*)out, n4);
}